// Round 1
// baseline (16206.512 us; speedup 1.0000x reference)
//
#include <hip/hip_runtime.h>
#include <math.h>

#define N_    128
#define CIN   64
#define COUT  128
#define CINT  32
#define S_    3
#define T_    64
#define V_    25
#define EPSF  1e-5f
#define LN1E4 9.210340371976184f

// result = lrelu( bn_a(conv(xa,w_a,b_a)) + bn_b(conv(xb,w_b,b_b)) )  pattern helper
__device__ __forceinline__ void bn_pair(const float* __restrict__ bn, const float* __restrict__ bias,
                                        int o, float& sc, float& sh) {
  float g = bn[o], be = bn[COUT + o], m = bn[2*COUT + o], vv = bn[3*COUT + o];
  sc = g / sqrtf(vv + EPSF);
  sh = (bias[o] - m) * sc + be;
}

// ---------------------------------------------------------------------------
// prep: pe_spatial [64][25], pe_temporal [128][64], transposed temporal qk
// weights wqkT[s][ci(128)][r(64)]  (r<32: q rows s*32+r ; r>=32: k rows 96+s*32+(r-32))
// ---------------------------------------------------------------------------
__global__ void k_prep(const float* __restrict__ w_qk_t,
                       float* __restrict__ pes, float* __restrict__ pet,
                       float* __restrict__ wqkT)
{
  int i = blockIdx.x * 256 + threadIdx.x;
  if (i < CIN * V_) {
    int c = i / V_, v = i % V_;
    float freq = expf(-(float)(c >> 1) * (2.0f * LN1E4 / (float)CIN));
    float arg = (float)v * freq;
    pes[i] = (c & 1) ? cosf(arg) : sinf(arg);
  } else if (i < CIN * V_ + COUT * T_) {
    int j = i - CIN * V_;
    int c = j >> 6, t = j & 63;
    float freq = expf(-(float)(c >> 1) * (2.0f * LN1E4 / (float)COUT));
    float arg = (float)t * freq;
    pet[j] = (c & 1) ? cosf(arg) : sinf(arg);
  } else if (i < CIN * V_ + COUT * T_ + S_ * COUT * 64) {
    int j = i - (CIN * V_ + COUT * T_);
    int r = j & 63;
    int ci = (j >> 6) & 127;
    int s = j >> 13;
    int gr = (r < CINT) ? (s * CINT + r) : (S_ * CINT + s * CINT + (r - CINT));
    wqkT[j] = w_qk_t[gr * COUT + ci];
  }
}

// ---------------------------------------------------------------------------
// Spatial attention logits, partial over t-chunks of 16.
// grid = N*S*4 ; partial[b][625], b = n*12 + s*4 + chunk
// ---------------------------------------------------------------------------
__global__ __launch_bounds__(256) void k_att_s_partial(
    const float* __restrict__ x, const float* __restrict__ pes,
    const float* __restrict__ wqk, const float* __restrict__ bqk,
    float* __restrict__ partial)
{
  int b = blockIdx.x;
  int chunk = b & 3;
  int s = (b >> 2) % S_;
  int n = b / 12;
  int tid = threadIdx.x;

  __shared__ __align__(16) float wlT[CIN][64];   // [ci][r]
  __shared__ float bias_l[64];
  __shared__ __align__(16) float xin[CIN][28];   // x+pe at time t, padded u
  __shared__ __align__(16) float qkt[64][28];    // rows 0..31 q, 32..63 k

  for (int i = tid; i < CIN * 64; i += 256) {
    int ci = i >> 6, r = i & 63;
    int gr = (r < CINT) ? (s * CINT + r) : (S_ * CINT + s * CINT + (r - CINT));
    wlT[ci][r] = wqk[gr * CIN + ci];
  }
  if (tid < 64) {
    int r = tid;
    int gr = (r < CINT) ? (s * CINT + r) : (S_ * CINT + s * CINT + (r - CINT));
    bias_l[r] = bqk[gr];
  }
  float accA[4][4];
#pragma unroll
  for (int a = 0; a < 4; ++a)
#pragma unroll
    for (int bb = 0; bb < 4; ++bb) accA[a][bb] = 0.f;

  int cu_r0 = (tid / 7) * 4;   // conv tile (tid < 112)
  int cu_u0 = (tid % 7) * 4;
  int at_u0 = (tid / 7) * 4;   // att tile (tid < 49)
  int at_v0 = (tid % 7) * 4;
  __syncthreads();

  int t0 = chunk * 16;
  for (int tt = 0; tt < 16; ++tt) {
    int t = t0 + tt;
    for (int i = tid; i < CIN * 28; i += 256) {
      int c = i / 28, u = i % 28;
      xin[c][u] = (u < V_) ? (x[((size_t)(n * CIN + c) * T_ + t) * V_ + u] + pes[c * V_ + u]) : 0.f;
    }
    __syncthreads();
    if (tid < 112) {
      float c4[4][4];
#pragma unroll
      for (int a = 0; a < 4; ++a)
#pragma unroll
        for (int bb = 0; bb < 4; ++bb) c4[a][bb] = 0.f;
#pragma unroll 4
      for (int ci = 0; ci < CIN; ++ci) {
        float4 w4 = *(const float4*)&wlT[ci][cu_r0];
        float4 x4 = *(const float4*)&xin[ci][cu_u0];
        const float* wp = (const float*)&w4;
        const float* xp = (const float*)&x4;
#pragma unroll
        for (int a = 0; a < 4; ++a)
#pragma unroll
          for (int bb = 0; bb < 4; ++bb) c4[a][bb] += wp[a] * xp[bb];
      }
#pragma unroll
      for (int a = 0; a < 4; ++a) {
        float bsv = bias_l[cu_r0 + a];
        float4 o4;
        o4.x = c4[a][0] + bsv; o4.y = c4[a][1] + bsv;
        o4.z = c4[a][2] + bsv; o4.w = c4[a][3] + bsv;
        *(float4*)&qkt[cu_r0 + a][cu_u0] = o4;
      }
    }
    __syncthreads();
    if (tid < 49) {
#pragma unroll 4
      for (int c = 0; c < CINT; ++c) {
        float4 q4 = *(const float4*)&qkt[c][at_u0];
        float4 k4 = *(const float4*)&qkt[CINT + c][at_v0];
        const float* qp = (const float*)&q4;
        const float* kp = (const float*)&k4;
#pragma unroll
        for (int a = 0; a < 4; ++a)
#pragma unroll
          for (int bb = 0; bb < 4; ++bb) accA[a][bb] += qp[a] * kp[bb];
      }
    }
    __syncthreads();
  }
  if (tid < 49) {
    size_t base = (size_t)b * 625;
#pragma unroll
    for (int a = 0; a < 4; ++a)
#pragma unroll
      for (int bb = 0; bb < 4; ++bb) {
        int u = at_u0 + a, v = at_v0 + bb;
        if (u < V_ && v < V_) partial[base + u * V_ + v] = accA[a][bb];
      }
  }
}

__global__ void k_att_s_final(const float* __restrict__ partial, const float* __restrict__ alphas,
                              const float* __restrict__ att0s, float* __restrict__ atts)
{
  int i = blockIdx.x * 256 + threadIdx.x;
  if (i >= N_ * S_ * 625) return;
  int uv = i % 625;
  int ns = i / 625;
  int s = ns % S_;
  const float* p = partial + (size_t)ns * 4 * 625;
  float sum = p[uv] + p[625 + uv] + p[1250 + uv] + p[1875 + uv];
  atts[i] = tanhf(sum * (1.f / 2048.f)) * alphas[s] + att0s[s * 625 + uv];
}

// ---------------------------------------------------------------------------
// Spatial merge: per (n,t) block.
// acc[s][c][v] = sum_u x[c][u]*att_s[s][u][v]; then
// y1 = lrelu( bn_outs(W_outs . acc) + bn_ds1(W_ds1 . x) )
// ---------------------------------------------------------------------------
__global__ __launch_bounds__(256) void k_merge_s(
    const float* __restrict__ x, const float* __restrict__ atts,
    const float* __restrict__ w_outs, const float* __restrict__ b_outs, const float* __restrict__ bn_outs,
    const float* __restrict__ w_ds1, const float* __restrict__ b_ds1, const float* __restrict__ bn_ds1,
    float* __restrict__ y1)
{
  int b = blockIdx.x, n = b / T_, t = b % T_;
  int tid = threadIdx.x;
  __shared__ __align__(16) float att2[S_ * V_][28];  // [s*25+u][v]
  __shared__ __align__(16) float xt[CIN][28];        // [c][u]
  __shared__ __align__(16) float xtT[V_][CIN + 4];   // [v][c]
  __shared__ __align__(16) float accT[V_][196];      // [v][s*64+c]
  __shared__ float sc_o[COUT], sh_o[COUT], sc_d[COUT], sh_d[COUT];

  for (int i = tid; i < S_ * V_ * 28; i += 256) {
    int row = i / 28, col = i % 28;
    att2[row][col] = (col < V_) ? atts[(size_t)n * (S_ * 625) + row * V_ + col] : 0.f;
  }
  for (int i = tid; i < CIN * 28; i += 256) {
    int c = i / 28, u = i % 28;
    float val = (u < V_) ? x[((size_t)(n * CIN + c) * T_ + t) * V_ + u] : 0.f;
    xt[c][u] = val;
    if (u < V_) xtT[u][c] = val;
  }
  if (tid < COUT) {
    float sc, sh;
    bn_pair(bn_outs, b_outs, tid, sc, sh); sc_o[tid] = sc; sh_o[tid] = sh;
    bn_pair(bn_ds1, b_ds1, tid, sc, sh);   sc_d[tid] = sc; sh_d[tid] = sh;
  }
  __syncthreads();
  // phase 1: einsum into accT
  for (int i = tid; i < S_ * CIN * 7; i += 256) {
    int vg = i % 7, sc2 = i / 7;
    int s = sc2 >> 6, c = sc2 & 63;
    int v0 = vg * 4;
    float r4[4] = {0.f, 0.f, 0.f, 0.f};
#pragma unroll 5
    for (int u = 0; u < V_; ++u) {
      float xv = xt[c][u];
      float4 a4 = *(const float4*)&att2[s * V_ + u][v0];
      r4[0] += xv * a4.x; r4[1] += xv * a4.y; r4[2] += xv * a4.z; r4[3] += xv * a4.w;
    }
#pragma unroll
    for (int j = 0; j < 4; ++j)
      if (v0 + j < V_) accT[v0 + j][sc2] = r4[j];
  }
  __syncthreads();
  // phase 2: conv + residual + bn + lrelu
  for (int i = tid; i < (COUT / 4) * V_; i += 256) {
    int og = i & 31, v = i >> 5, o = og * 4;
    float aB[4] = {0.f, 0.f, 0.f, 0.f}, aD[4] = {0.f, 0.f, 0.f, 0.f};
    const float* arow = accT[v];
#pragma unroll 4
    for (int k2 = 0; k2 < S_ * CIN; k2 += 4) {
      float4 a4 = *(const float4*)&arow[k2];
#pragma unroll
      for (int j = 0; j < 4; ++j) {
        float4 w4 = *(const float4*)&w_outs[(size_t)(o + j) * (S_ * CIN) + k2];
        aB[j] += w4.x * a4.x + w4.y * a4.y + w4.z * a4.z + w4.w * a4.w;
      }
    }
    const float* xrow = xtT[v];
#pragma unroll 4
    for (int k2 = 0; k2 < CIN; k2 += 4) {
      float4 a4 = *(const float4*)&xrow[k2];
#pragma unroll
      for (int j = 0; j < 4; ++j) {
        float4 w4 = *(const float4*)&w_ds1[(size_t)(o + j) * CIN + k2];
        aD[j] += w4.x * a4.x + w4.y * a4.y + w4.z * a4.z + w4.w * a4.w;
      }
    }
#pragma unroll
    for (int j = 0; j < 4; ++j) {
      float val = aB[j] * sc_o[o + j] + sh_o[o + j] + aD[j] * sc_d[o + j] + sh_d[o + j];
      val = (val >= 0.f) ? val : 0.1f * val;
      y1[((size_t)(n * COUT + o + j) * T_ + t) * V_ + v] = val;
    }
  }
}

// ---------------------------------------------------------------------------
// out = lrelu( bn_a(conv(xa[CA ch], w_a)) + bn_b(conv(xb[CB ch], w_b)) )
// per (n,t) block.  D: xa=x(64,w_ds2), xb=y1(128,w_ffs) -> y
//                   F: xa=y(128,w_dt2), xb=z1(128,w_fft) -> d_out
// ---------------------------------------------------------------------------
template <int CA, int CB>
__global__ __launch_bounds__(256) void k_resid_ff(
    const float* __restrict__ xa, const float* __restrict__ xb,
    const float* __restrict__ w_a, const float* __restrict__ b_a, const float* __restrict__ bn_a,
    const float* __restrict__ w_b, const float* __restrict__ b_b, const float* __restrict__ bn_b,
    float* __restrict__ out)
{
  int b = blockIdx.x, n = b / T_, t = b % T_;
  int tid = threadIdx.x;
  __shared__ __align__(16) float xaT[V_][CA + 4];
  __shared__ __align__(16) float xbT[V_][CB + 4];
  __shared__ float sa_[COUT], ha_[COUT], sb_[COUT], hb_[COUT];

  for (int i = tid; i < CA * V_; i += 256) {
    int c = i / V_, v = i % V_;
    xaT[v][c] = xa[((size_t)(n * CA + c) * T_ + t) * V_ + v];
  }
  for (int i = tid; i < CB * V_; i += 256) {
    int c = i / V_, v = i % V_;
    xbT[v][c] = xb[((size_t)(n * CB + c) * T_ + t) * V_ + v];
  }
  if (tid < COUT) {
    float sc, sh;
    bn_pair(bn_a, b_a, tid, sc, sh); sa_[tid] = sc; ha_[tid] = sh;
    bn_pair(bn_b, b_b, tid, sc, sh); sb_[tid] = sc; hb_[tid] = sh;
  }
  __syncthreads();
  for (int i = tid; i < (COUT / 4) * V_; i += 256) {
    int og = i & 31, v = i >> 5, o = og * 4;
    float aB[4] = {0.f, 0.f, 0.f, 0.f}, aA[4] = {0.f, 0.f, 0.f, 0.f};
#pragma unroll 4
    for (int k2 = 0; k2 < CB; k2 += 4) {
      float4 a4 = *(const float4*)&xbT[v][k2];
#pragma unroll
      for (int j = 0; j < 4; ++j) {
        float4 w4 = *(const float4*)&w_b[(size_t)(o + j) * CB + k2];
        aB[j] += w4.x * a4.x + w4.y * a4.y + w4.z * a4.z + w4.w * a4.w;
      }
    }
#pragma unroll 4
    for (int k2 = 0; k2 < CA; k2 += 4) {
      float4 a4 = *(const float4*)&xaT[v][k2];
#pragma unroll
      for (int j = 0; j < 4; ++j) {
        float4 w4 = *(const float4*)&w_a[(size_t)(o + j) * CA + k2];
        aA[j] += w4.x * a4.x + w4.y * a4.y + w4.z * a4.z + w4.w * a4.w;
      }
    }
#pragma unroll
    for (int j = 0; j < 4; ++j) {
      float val = aA[j] * sa_[o + j] + ha_[o + j] + aB[j] * sb_[o + j] + hb_[o + j];
      val = (val >= 0.f) ? val : 0.1f * val;
      out[((size_t)(n * COUT + o + j) * T_ + t) * V_ + v] = val;
    }
  }
}

// ---------------------------------------------------------------------------
// Temporal attention logits, partial over v-chunks (13 / 12).
// grid = N*S*2 ; partial[b][64*64], b = n*6 + s*2 + chunk
// ---------------------------------------------------------------------------
__global__ __launch_bounds__(256) void k_att_t_partial(
    const float* __restrict__ y, const float* __restrict__ pet,
    const float* __restrict__ wqkT, const float* __restrict__ bqk,
    float* __restrict__ partial)
{
  int b = blockIdx.x;
  int chunk = b & 1;
  int s = (b >> 1) % S_;
  int n = b / 6;
  int tid = threadIdx.x;
  int v0 = chunk ? 13 : 0;
  int nv = chunk ? 12 : 13;

  __shared__ __align__(16) float yin[COUT][T_];   // y+pe_t for fixed v: [ci][t]
  __shared__ __align__(16) float qk[64][T_];      // rows 0..31 q, 32..63 k : [row][t]
  __shared__ float bias_l[64];

  if (tid < 64) {
    int r = tid;
    bias_l[r] = (r < CINT) ? bqk[s * CINT + r] : bqk[S_ * CINT + s * CINT + (r - CINT)];
  }
  int rg = tid >> 4;          // conv: rows rg*4..+3
  int r0 = rg * 4;
  int t0c = (tid & 15) * 4;   // conv: t t0c..+3 ; att: q columns q0=t0c
  float accA[4][4];
#pragma unroll
  for (int a = 0; a < 4; ++a)
#pragma unroll
    for (int bb = 0; bb < 4; ++bb) accA[a][bb] = 0.f;

  for (int vv = 0; vv < nv; ++vv) {
    int v = v0 + vv;
    __syncthreads();  // prior att readers of qk done; bias_l visible
    for (int i = tid; i < COUT * T_; i += 256) {
      int ci = i >> 6, t = i & 63;
      yin[ci][t] = y[((size_t)(n * COUT + ci) * T_ + t) * V_ + v] + pet[i];
    }
    __syncthreads();
    float c4[4][4];
#pragma unroll
    for (int a = 0; a < 4; ++a)
#pragma unroll
      for (int bb = 0; bb < 4; ++bb) c4[a][bb] = 0.f;
#pragma unroll 4
    for (int ci = 0; ci < COUT; ++ci) {
      float4 w4 = *(const float4*)&wqkT[((size_t)(s * COUT + ci)) * 64 + r0];
      float4 y4 = *(const float4*)&yin[ci][t0c];
      const float* wp = (const float*)&w4;
      const float* yp = (const float*)&y4;
#pragma unroll
      for (int a = 0; a < 4; ++a)
#pragma unroll
        for (int bb = 0; bb < 4; ++bb) c4[a][bb] += wp[a] * yp[bb];
    }
#pragma unroll
    for (int a = 0; a < 4; ++a) {
      float bsv = bias_l[r0 + a];
      float4 o4;
      o4.x = c4[a][0] + bsv; o4.y = c4[a][1] + bsv;
      o4.z = c4[a][2] + bsv; o4.w = c4[a][3] + bsv;
      *(float4*)&qk[r0 + a][t0c] = o4;
    }
    __syncthreads();
#pragma unroll 4
    for (int c = 0; c < CINT; ++c) {
      float4 q4 = *(const float4*)&qk[c][r0];          // t tile = rg*4
      float4 k4 = *(const float4*)&qk[CINT + c][t0c];  // q tile
      const float* qp = (const float*)&q4;
      const float* kp = (const float*)&k4;
#pragma unroll
      for (int a = 0; a < 4; ++a)
#pragma unroll
        for (int bb = 0; bb < 4; ++bb) accA[a][bb] += qp[a] * kp[bb];
    }
  }
  size_t base = (size_t)b * (T_ * T_);
#pragma unroll
  for (int a = 0; a < 4; ++a)
#pragma unroll
    for (int bb = 0; bb < 4; ++bb)
      partial[base + (size_t)(r0 + a) * T_ + (t0c + bb)] = accA[a][bb];
}

__global__ void k_att_t_final(const float* __restrict__ partial, const float* __restrict__ alphat,
                              const float* __restrict__ att0t, float* __restrict__ attt)
{
  int i = blockIdx.x * 256 + threadIdx.x;
  if (i >= N_ * S_ * T_ * T_) return;
  int tq = i % (T_ * T_);
  int ns = i / (T_ * T_);
  int s = ns % S_;
  const float* p = partial + (size_t)ns * 2 * (T_ * T_);
  float sum = p[tq] + p[T_ * T_ + tq];
  attt[i] = tanhf(sum * (1.f / 800.f)) * alphat[s] + att0t[s * T_ * T_ + tq];
}

// ---------------------------------------------------------------------------
// Temporal merge: per (n,q) block.
// acc[s][c][v] = sum_t att_t[s][t][q]*y[c][t][v]; then
// z1 = lrelu( bn_outt(W_outt . acc) + bn_dt1(W_dt1 . y[:,q,:]) )
// ---------------------------------------------------------------------------
__global__ __launch_bounds__(256) void k_merge_t(
    const float* __restrict__ y, const float* __restrict__ attt,
    const float* __restrict__ w_outt, const float* __restrict__ b_outt, const float* __restrict__ bn_outt,
    const float* __restrict__ w_dt1, const float* __restrict__ b_dt1, const float* __restrict__ bn_dt1,
    float* __restrict__ z1)
{
  int b = blockIdx.x, n = b / T_, q = b % T_;
  int tid = threadIdx.x;
  __shared__ float attq[S_][T_];
  __shared__ __align__(16) float yqT[V_][COUT + 4];
  __shared__ __align__(16) float accT[V_][388];   // [v][s*128+c]
  __shared__ float sc_o[COUT], sh_o[COUT], sc_d[COUT], sh_d[COUT];

  if (tid < S_ * T_) {
    int s = tid / T_, t = tid % T_;
    attq[s][t] = attt[((size_t)(n * S_ + s) * T_ + t) * T_ + q];
  }
  for (int i = tid; i < COUT * V_; i += 256) {
    int c = i / V_, v = i % V_;
    yqT[v][c] = y[((size_t)(n * COUT + c) * T_ + q) * V_ + v];
  }
  if (tid < COUT) {
    float sc, sh;
    bn_pair(bn_outt, b_outt, tid, sc, sh); sc_o[tid] = sc; sh_o[tid] = sh;
    bn_pair(bn_dt1, b_dt1, tid, sc, sh);   sc_d[tid] = sc; sh_d[tid] = sh;
  }
  float racc0[13], racc1[13], racc2[13];
  size_t offk[13];
#pragma unroll
  for (int k = 0; k < 13; ++k) {
    racc0[k] = racc1[k] = racc2[k] = 0.f;
    offk[k] = 0;
    int p = k * 256 + tid;
    if (p < COUT * V_) offk[k] = ((size_t)(n * COUT + p / V_) * T_) * V_ + (p % V_);
  }
  __syncthreads();
  // phase 1: rank-1 accumulation over t (y read direct from global/L2)
  for (int t = 0; t < T_; ++t) {
    float a0 = attq[0][t], a1 = attq[1][t], a2 = attq[2][t];
#pragma unroll
    for (int k = 0; k < 13; ++k) {
      int p = k * 256 + tid;
      if (p < COUT * V_) {
        float yv = y[offk[k] + (size_t)t * V_];
        racc0[k] += a0 * yv; racc1[k] += a1 * yv; racc2[k] += a2 * yv;
      }
    }
  }
#pragma unroll
  for (int k = 0; k < 13; ++k) {
    int p = k * 256 + tid;
    if (p < COUT * V_) {
      int c = p / V_, v = p % V_;
      accT[v][c] = racc0[k];
      accT[v][COUT + c] = racc1[k];
      accT[v][2 * COUT + c] = racc2[k];
    }
  }
  __syncthreads();
  // phase 2
  for (int i = tid; i < (COUT / 4) * V_; i += 256) {
    int og = i & 31, v = i >> 5, o = og * 4;
    float aB[4] = {0.f, 0.f, 0.f, 0.f}, aD[4] = {0.f, 0.f, 0.f, 0.f};
    const float* arow = accT[v];
#pragma unroll 4
    for (int k2 = 0; k2 < S_ * COUT; k2 += 4) {
      float4 a4 = *(const float4*)&arow[k2];
#pragma unroll
      for (int j = 0; j < 4; ++j) {
        float4 w4 = *(const float4*)&w_outt[(size_t)(o + j) * (S_ * COUT) + k2];
        aB[j] += w4.x * a4.x + w4.y * a4.y + w4.z * a4.z + w4.w * a4.w;
      }
    }
    const float* yrow = yqT[v];
#pragma unroll 4
    for (int k2 = 0; k2 < COUT; k2 += 4) {
      float4 a4 = *(const float4*)&yrow[k2];
#pragma unroll
      for (int j = 0; j < 4; ++j) {
        float4 w4 = *(const float4*)&w_dt1[(size_t)(o + j) * COUT + k2];
        aD[j] += w4.x * a4.x + w4.y * a4.y + w4.z * a4.z + w4.w * a4.w;
      }
    }
#pragma unroll
    for (int j = 0; j < 4; ++j) {
      float val = aB[j] * sc_o[o + j] + sh_o[o + j] + aD[j] * sc_d[o + j] + sh_d[o + j];
      val = (val >= 0.f) ? val : 0.1f * val;
      z1[((size_t)(n * COUT + o + j) * T_ + q) * V_ + v] = val;
    }
  }
}

// ---------------------------------------------------------------------------
extern "C" void kernel_launch(void* const* d_in, const int* in_sizes, int n_in,
                              void* d_out, int out_size, void* d_ws, size_t ws_size,
                              hipStream_t stream)
{
  const float* x       = (const float*)d_in[0];
  const float* w_qk_s  = (const float*)d_in[1];
  const float* b_qk_s  = (const float*)d_in[2];
  const float* alphas  = (const float*)d_in[3];
  const float* att0s   = (const float*)d_in[4];
  const float* w_outs  = (const float*)d_in[5];
  const float* b_outs  = (const float*)d_in[6];
  const float* bn_outs = (const float*)d_in[7];
  const float* w_ffs   = (const float*)d_in[8];
  const float* b_ffs   = (const float*)d_in[9];
  const float* bn_ffs  = (const float*)d_in[10];
  const float* w_ds1   = (const float*)d_in[11];
  const float* b_ds1   = (const float*)d_in[12];
  const float* bn_ds1  = (const float*)d_in[13];
  const float* w_ds2   = (const float*)d_in[14];
  const float* b_ds2   = (const float*)d_in[15];
  const float* bn_ds2  = (const float*)d_in[16];
  const float* w_qk_t  = (const float*)d_in[17];
  const float* b_qk_t  = (const float*)d_in[18];
  const float* alphat  = (const float*)d_in[19];
  const float* att0t   = (const float*)d_in[20];
  const float* w_outt  = (const float*)d_in[21];
  const float* b_outt  = (const float*)d_in[22];
  const float* bn_outt = (const float*)d_in[23];
  const float* w_fft   = (const float*)d_in[24];
  const float* b_fft   = (const float*)d_in[25];
  const float* bn_fft  = (const float*)d_in[26];
  const float* w_dt1   = (const float*)d_in[27];
  const float* b_dt1   = (const float*)d_in[28];
  const float* bn_dt1  = (const float*)d_in[29];
  const float* w_dt2   = (const float*)d_in[30];
  const float* b_dt2   = (const float*)d_in[31];
  const float* bn_dt2  = (const float*)d_in[32];

  // workspace layout (floats); total 58,381,760 floats = 233.5 MB
  float* ws    = (float*)d_ws;
  float* pes   = ws + 0;          //  1600
  float* pet   = ws + 1600;       //  8192
  float* wqkT  = ws + 9792;       //  24576
  float* partA = ws + 34368;      //  1536*625  = 960000
  float* partB = ws + 994368;     //  768*4096  = 3145728
  float* atts  = ws + 4140096;    //  128*3*625 = 240000
  float* attt  = ws + 4380096;    //  128*3*4096= 1572864
  float* y1    = ws + 5952960;    //  26214400  (also reused as z1)
  float* y     = ws + 32167360;   //  26214400

  k_prep<<<(34368 + 255) / 256, 256, 0, stream>>>(w_qk_t, pes, pet, wqkT);

  // spatial attention
  k_att_s_partial<<<N_ * S_ * 4, 256, 0, stream>>>(x, pes, w_qk_s, b_qk_s, partA);
  k_att_s_final<<<(N_ * S_ * 625 + 255) / 256, 256, 0, stream>>>(partA, alphas, att0s, atts);
  k_merge_s<<<N_ * T_, 256, 0, stream>>>(x, atts,
                                         w_outs, b_outs, bn_outs,
                                         w_ds1, b_ds1, bn_ds1, y1);
  // y = lrelu(bn_ds2(conv(x)) + bn_ffs(conv(y1)))
  k_resid_ff<CIN, COUT><<<N_ * T_, 256, 0, stream>>>(x, y1,
                                                     w_ds2, b_ds2, bn_ds2,
                                                     w_ffs, b_ffs, bn_ffs, y);
  // temporal attention
  k_att_t_partial<<<N_ * S_ * 2, 256, 0, stream>>>(y, pet, wqkT, b_qk_t, partB);
  k_att_t_final<<<(N_ * S_ * T_ * T_ + 255) / 256, 256, 0, stream>>>(partB, alphat, att0t, attt);
  k_merge_t<<<N_ * T_, 256, 0, stream>>>(y, attt,
                                         w_outt, b_outt, bn_outt,
                                         w_dt1, b_dt1, bn_dt1, y1);
  // out = lrelu(bn_dt2(conv(y)) + bn_fft(conv(z1)))
  k_resid_ff<COUT, COUT><<<N_ * T_, 256, 0, stream>>>(y, y1,
                                                      w_dt2, b_dt2, bn_dt2,
                                                      w_fft, b_fft, bn_fft, (float*)d_out);
}

// Round 3
// 1131.026 us; speedup vs baseline: 14.3290x; 14.3290x over previous
//
#include <hip/hip_runtime.h>
#include <math.h>

#define N_    128
#define CIN   64
#define COUT  128
#define CINT  32
#define S_    3
#define T_    64
#define V_    25
#define EPSF  1e-5f
#define LN1E4 9.210340371976184f
#define P_    (N_*T_*V_)   // 204800 positions

typedef __attribute__((ext_vector_type(8))) short bf16x8;
typedef __attribute__((ext_vector_type(4))) unsigned short bf16x4;
typedef __attribute__((ext_vector_type(4))) float f32x4;

#define MFMA(a,b,c) __builtin_amdgcn_mfma_f32_16x16x32_bf16(a,b,c,0,0,0)

// ---- workspace byte offsets --------------------------------------------------
// sizes: bf16 [pos][64]=26,214,400 B ; [pos][128]=52,428,800 B ; [pos][192]=78,643,200 B
#define OFF_WQS    0u          // 192x64 bf16          -> 24576
#define OFF_WQT    24576u      // 192x128              -> 73728
#define OFF_WOUTS  73728u      // 128x192 prescaled    -> 122880
#define OFF_WDS1   122880u     // 128x64               -> 139264
#define OFF_WFFS   139264u     // 128x128              -> 172032
#define OFF_WDS2   172032u     // 128x64               -> 188416
#define OFF_WOUTT  188416u     // 128x384              -> 286720
#define OFF_WDT1   286720u     // 128x128              -> 319488
#define OFF_WFFT   319488u     // 128x128              -> 352256
#define OFF_WDT2   352256u     // 128x128              -> 385024
#define OFF_SHS    385024u     // fp32 192x32          -> 409600
#define OFF_SHT    409600u     // fp32 192x64          -> 458752
#define OFF_SHA    458752u
#define OFF_SHB    459264u
#define OFF_SHC    459776u
#define OFF_SHD    460288u     //                      -> 460800
#define OFF_ATTST  460800u     // [n][s][32v][32u] bf16 -> 1247232
#define OFF_ATTTT  1247232u    // [n][s][64q][64t] bf16 -> 4392960
#define OFF_XCL    4392960u    // [pos][64]  bf16       -> 30607360
#define OFF_YCL    30607360u   // [pos][128] bf16 (y)   -> 83036160
#define OFF_RB     83036160u   // [pos][128] bf16 (y1 then z1) -> 135464960
#define OFF_RA     135464960u  // [pos][192] bf16 (qk_s -> ys -> qk_t) -> 214108160 (+spill pad)

__device__ __forceinline__ unsigned short f2bf(float f) {
  union { float f; unsigned int u; } v; v.f = f;
  unsigned int u = v.u;
  return (unsigned short)((u + 0x7FFFu + ((u >> 16) & 1u)) >> 16);
}
__device__ __forceinline__ float bnscale(const float* bn, int o) {
  return bn[o] * rsqrtf(bn[3*COUT + o] + EPSF);
}
__device__ __forceinline__ float bnshift(const float* bn, const float* b, int o) {
  return (b[o] - bn[2*COUT + o]) * bnscale(bn, o) + bn[COUT + o];
}
__device__ __forceinline__ float pe_val(int c, int p, float inv) {
  float freq = expf(-(float)(c >> 1) * inv);
  float arg = (float)p * freq;
  return (c & 1) ? cosf(arg) : sinf(arg);
}

// =============================================================================
// prep: bf16 weights (BN-prescaled), fp32 shifts with PE folded into qk biases
// =============================================================================
__global__ __launch_bounds__(256) void k_prep(
    const float* __restrict__ wqks, const float* __restrict__ bqks,
    const float* __restrict__ wouts, const float* __restrict__ bouts, const float* __restrict__ bnouts,
    const float* __restrict__ wffs, const float* __restrict__ bffs, const float* __restrict__ bnffs,
    const float* __restrict__ wds1, const float* __restrict__ bds1, const float* __restrict__ bnds1,
    const float* __restrict__ wds2, const float* __restrict__ bds2, const float* __restrict__ bnds2,
    const float* __restrict__ wqkt, const float* __restrict__ bqkt,
    const float* __restrict__ woutt, const float* __restrict__ boutt, const float* __restrict__ bnoutt,
    const float* __restrict__ wfft, const float* __restrict__ bfft, const float* __restrict__ bnfft,
    const float* __restrict__ wdt1, const float* __restrict__ bdt1, const float* __restrict__ bndt1,
    const float* __restrict__ wdt2, const float* __restrict__ bdt2, const float* __restrict__ bndt2,
    char* __restrict__ ws)
{
  int i = blockIdx.x * 256 + threadIdx.x;
  unsigned short* WQS   = (unsigned short*)(ws + OFF_WQS);
  unsigned short* WQT   = (unsigned short*)(ws + OFF_WQT);
  unsigned short* WOUTS = (unsigned short*)(ws + OFF_WOUTS);
  unsigned short* WDS1  = (unsigned short*)(ws + OFF_WDS1);
  unsigned short* WFFS  = (unsigned short*)(ws + OFF_WFFS);
  unsigned short* WDS2  = (unsigned short*)(ws + OFF_WDS2);
  unsigned short* WOUTT = (unsigned short*)(ws + OFF_WOUTT);
  unsigned short* WDT1  = (unsigned short*)(ws + OFF_WDT1);
  unsigned short* WFFT  = (unsigned short*)(ws + OFF_WFFT);
  unsigned short* WDT2  = (unsigned short*)(ws + OFF_WDT2);
  float* SHS = (float*)(ws + OFF_SHS);
  float* SHT = (float*)(ws + OFF_SHT);
  float* SHA = (float*)(ws + OFF_SHA);
  float* SHB = (float*)(ws + OFF_SHB);
  float* SHC = (float*)(ws + OFF_SHC);
  float* SHD = (float*)(ws + OFF_SHD);

  if (i < 12288) { WQS[i] = f2bf(wqks[i]); }
  else if (i < 36864) { int j = i - 12288; WQT[j] = f2bf(wqkt[j]); }
  else if (i < 61440) { int j = i - 36864; int o = j / 192; WOUTS[j] = f2bf(wouts[j] * bnscale(bnouts, o)); }
  else if (i < 69632) { int j = i - 61440; int o = j / 64;  WDS1[j]  = f2bf(wds1[j]  * bnscale(bnds1, o)); }
  else if (i < 86016) { int j = i - 69632; int o = j / 128; WFFS[j]  = f2bf(wffs[j]  * bnscale(bnffs, o)); }
  else if (i < 94208) { int j = i - 86016; int o = j / 64;  WDS2[j]  = f2bf(wds2[j]  * bnscale(bnds2, o)); }
  else if (i < 143360){ int j = i - 94208; int o = j / 384; WOUTT[j] = f2bf(woutt[j] * bnscale(bnoutt, o)); }
  else if (i < 159744){ int j = i - 143360; int o = j / 128; WDT1[j] = f2bf(wdt1[j] * bnscale(bndt1, o)); }
  else if (i < 176128){ int j = i - 159744; int o = j / 128; WFFT[j] = f2bf(wfft[j] * bnscale(bnfft, o)); }
  else if (i < 192512){ int j = i - 176128; int o = j / 128; WDT2[j] = f2bf(wdt2[j] * bnscale(bndt2, o)); }
  else if (i < 198656){ // shiftS[r][u]: bias + conv(pe_s)
    int j = i - 192512; int r = j >> 5, u = j & 31;
    float acc = 0.f;
    if (u < V_) {
      acc = bqks[r];
      const float inv = 2.0f * LN1E4 / (float)CIN;
      for (int c = 0; c < CIN; ++c) acc += wqks[r*CIN + c] * pe_val(c, u, inv);
    }
    SHS[j] = acc;
  }
  else if (i < 210944){ // shiftT[r][t]
    int j = i - 198656; int r = j >> 6, t = j & 63;
    float acc = bqkt[r];
    const float inv = 2.0f * LN1E4 / (float)COUT;
    for (int c = 0; c < COUT; ++c) acc += wqkt[r*COUT + c] * pe_val(c, t, inv);
    SHT[j] = acc;
  }
  else if (i < 211456){
    int j = i - 210944; int o = j & 127; int g = j >> 7;
    if (g == 0) SHA[o] = bnshift(bnouts, bouts, o) + bnshift(bnds1, bds1, o);
    if (g == 1) SHB[o] = bnshift(bnffs, bffs, o)   + bnshift(bnds2, bds2, o);
    if (g == 2) SHC[o] = bnshift(bnoutt, boutt, o) + bnshift(bndt1, bdt1, o);
    if (g == 3) SHD[o] = bnshift(bnfft, bfft, o)   + bnshift(bndt2, bdt2, o);
  }
}

// =============================================================================
// convert x fp32 NCTV -> x_cl [pos][64] bf16
// =============================================================================
__global__ __launch_bounds__(256) void k_convert(const float* __restrict__ x,
                                                 unsigned short* __restrict__ xcl)
{
  __shared__ float xs[64][26];
  int b = blockIdx.x; int n = b >> 6, t = b & 63; int tid = threadIdx.x;
  for (int i = tid; i < 1600; i += 256) {
    int c = i / 25, v = i % 25;
    xs[c][v] = x[(((size_t)(n*64 + c))*64 + t)*25 + v];
  }
  __syncthreads();
  size_t clbase = ((size_t)(n*64 + t)) * 1600;
  for (int i = tid; i < 1600; i += 256) { int v = i >> 6, c = i & 63; xcl[clbase + i] = f2bf(xs[c][v]); }
}

// =============================================================================
// generic dual GEMM-BT conv: out[pos][o] = f( A1.W1^T + A2.W2^T + shift )
// SMODE: 0 shift[o], 1 shift[o*32+v], 2 shift[o*64+t]
// OMODE: 0 bf16 CL, 2 fp32 NCTV
// =============================================================================
template<int K1, int K2, int NO, int SMODE, int LRELU, int OMODE>
__global__ __launch_bounds__(256) void k_conv(
    const unsigned short* __restrict__ A1, const unsigned short* __restrict__ A2,
    const unsigned short* __restrict__ W1, const unsigned short* __restrict__ W2,
    const float* __restrict__ shift, void* __restrict__ outp)
{
  const int lane = threadIdx.x & 63;
  const int wave = threadIdx.x >> 6;
  const int col  = lane & 15;
  const int quad = lane >> 4;
  const int pos0 = blockIdx.x * 64 + wave * 16;

  constexpr int NK1 = K1 / 32;
  constexpr int NK2 = (K2 > 0) ? (K2 / 32) : 1;
  bf16x8 a1[NK1];
  bf16x8 a2[NK2];
  {
    const unsigned short* p = A1 + (size_t)(pos0 + col) * K1 + quad * 8;
#pragma unroll
    for (int ks = 0; ks < NK1; ++ks) a1[ks] = *(const bf16x8*)(p + ks * 32);
  }
  if constexpr (K2 > 0) {
    const unsigned short* p = A2 + (size_t)(pos0 + col) * K2 + quad * 8;
#pragma unroll
    for (int ks = 0; ks < K2 / 32; ++ks) a2[ks] = *(const bf16x8*)(p + ks * 32);
  }

  for (int ot = 0; ot < NO / 16; ++ot) {
    f32x4 acc = {0.f, 0.f, 0.f, 0.f};
    const unsigned short* w1p = W1 + (size_t)(ot * 16 + col) * K1 + quad * 8;
#pragma unroll
    for (int ks = 0; ks < NK1; ++ks)
      acc = MFMA(a1[ks], *(const bf16x8*)(w1p + ks * 32), acc);
    if constexpr (K2 > 0) {
      const unsigned short* w2p = W2 + (size_t)(ot * 16 + col) * K2 + quad * 8;
#pragma unroll
      for (int ks = 0; ks < K2 / 32; ++ks)
        acc = MFMA(a2[ks], *(const bf16x8*)(w2p + ks * 32), acc);
    }
    const int o = ot * 16 + col;
#pragma unroll
    for (int r = 0; r < 4; ++r) {
      int pos = pos0 + quad * 4 + r;
      float val = acc[r];
      int rem = pos % 1600;
      int t = rem / 25, v = rem % 25;
      if constexpr (SMODE == 0)      val += shift[o];
      else if constexpr (SMODE == 1) val += shift[o * 32 + v];
      else                           val += shift[o * 64 + t];
      if constexpr (LRELU) val = (val >= 0.f) ? val : 0.1f * val;
      if constexpr (OMODE == 2) {
        int n = pos / 1600;
        ((float*)outp)[(((size_t)(n * 128 + o)) * 64 + t) * 25 + v] = val;
      } else {
        ((unsigned short*)outp)[(size_t)pos * NO + o] = f2bf(val);
      }
    }
  }
}

// =============================================================================
// spatial attention logits: per (n,s), C[u25][v25], K=(t64 x c32)
// out: att_sT[n][s][v(32)][u(32)] bf16, tanh-scaled, u>=25 zeroed
// =============================================================================
__global__ __launch_bounds__(64) void k_att_s(const unsigned short* __restrict__ qks,
                                              const float* __restrict__ alphas,
                                              const float* __restrict__ att0s,
                                              unsigned short* __restrict__ attsT)
{
  int b = blockIdx.x; int n = b / 3, s = b % 3;
  int lane = threadIdx.x; int col = lane & 15, quad = lane >> 4;
  f32x4 acc[2][2];
#pragma unroll
  for (int a = 0; a < 2; ++a)
#pragma unroll
    for (int c = 0; c < 2; ++c) acc[a][c] = (f32x4){0.f, 0.f, 0.f, 0.f};

  for (int t = 0; t < 64; ++t) {
    size_t rowb = ((size_t)(n * 64 + t)) * 25;
    bf16x8 afr[2], bfr[2];
#pragma unroll
    for (int ut = 0; ut < 2; ++ut)
      afr[ut] = *(const bf16x8*)(qks + (rowb + ut * 16 + col) * 192 + s * 32 + quad * 8);
#pragma unroll
    for (int vt = 0; vt < 2; ++vt)
      bfr[vt] = *(const bf16x8*)(qks + (rowb + vt * 16 + col) * 192 + 96 + s * 32 + quad * 8);
#pragma unroll
    for (int ut = 0; ut < 2; ++ut)
#pragma unroll
      for (int vt = 0; vt < 2; ++vt)
        acc[ut][vt] = MFMA(afr[ut], bfr[vt], acc[ut][vt]);
  }
  float alpha = alphas[s];
#pragma unroll
  for (int ut = 0; ut < 2; ++ut)
#pragma unroll
    for (int vt = 0; vt < 2; ++vt)
#pragma unroll
      for (int r = 0; r < 4; ++r) {
        int u = ut * 16 + quad * 4 + r;
        int v = vt * 16 + col;
        if (v < V_) {
          float val = 0.f;
          if (u < V_)
            val = tanhf(acc[ut][vt][r] * (1.0f / 2048.0f)) * alpha + att0s[(s * 25 + u) * 25 + v];
          attsT[((size_t)((n * 3 + s) * 32) + v) * 32 + u] = f2bf(val);
        }
      }
}

// =============================================================================
// spatial einsum: per (n,t): ys[v][s*64+c] = sum_u att_sT[s][v][u] * x[c][t][u]
// x read directly as fp32 (clamped u<25)
// =============================================================================
__global__ __launch_bounds__(64) void k_einsum_s(const float* __restrict__ x,
                                                 const unsigned short* __restrict__ attsT,
                                                 unsigned short* __restrict__ ys)
{
  int b = blockIdx.x; int n = b >> 6, t = b & 63;
  int lane = threadIdx.x; int col = lane & 15, quad = lane >> 4;
  bf16x8 bfr[4];
#pragma unroll
  for (int ct = 0; ct < 4; ++ct) {
    const float* p = x + ((size_t)(n * 64 + ct * 16 + col) * 64 + t) * 25;
    bf16x8 f;
#pragma unroll
    for (int j = 0; j < 8; ++j) {
      int u = quad * 8 + j;
      f[j] = (u < V_) ? (short)f2bf(p[u]) : (short)0;
    }
    bfr[ct] = f;
  }
  size_t posbase = ((size_t)(n * 64 + t)) * 25;
#pragma unroll
  for (int s = 0; s < 3; ++s) {
    bf16x8 afr[2];
#pragma unroll
    for (int vt = 0; vt < 2; ++vt)
      afr[vt] = *(const bf16x8*)(attsT + ((size_t)((n * 3 + s) * 32) + vt * 16 + col) * 32 + quad * 8);
#pragma unroll
    for (int vt = 0; vt < 2; ++vt)
#pragma unroll
      for (int ct = 0; ct < 4; ++ct) {
        f32x4 acc = {0.f, 0.f, 0.f, 0.f};
        acc = MFMA(afr[vt], bfr[ct], acc);
#pragma unroll
        for (int r = 0; r < 4; ++r) {
          int v = vt * 16 + quad * 4 + r;
          if (v < V_)
            ys[(posbase + v) * 192 + s * 64 + ct * 16 + col] = f2bf(acc[r]);
        }
      }
  }
}

// =============================================================================
// temporal attention logits: per (n,s): C[t64][q64], K=(v25 x c32)
// out att_tT[n][s][q][t] bf16
// =============================================================================
__global__ __launch_bounds__(256) void k_att_t(const unsigned short* __restrict__ qkt,
                                               const float* __restrict__ alphat,
                                               const float* __restrict__ att0t,
                                               unsigned short* __restrict__ atttT)
{
  int b = blockIdx.x; int n = b / 3, s = b % 3;
  int wave = threadIdx.x >> 6; int lane = threadIdx.x & 63;
  int col = lane & 15, quad = lane >> 4;
  int mt = wave;
  f32x4 acc[4];
#pragma unroll
  for (int q = 0; q < 4; ++q) acc[q] = (f32x4){0.f, 0.f, 0.f, 0.f};

  for (int v = 0; v < V_; ++v) {
    bf16x8 a = *(const bf16x8*)(qkt + (((size_t)(n * 64 + mt * 16 + col)) * 25 + v) * 192 + s * 32 + quad * 8);
#pragma unroll
    for (int nt = 0; nt < 4; ++nt) {
      bf16x8 bb = *(const bf16x8*)(qkt + (((size_t)(n * 64 + nt * 16 + col)) * 25 + v) * 192 + 96 + s * 32 + quad * 8);
      acc[nt] = MFMA(a, bb, acc[nt]);
    }
  }
  float alpha = alphat[s];
#pragma unroll
  for (int nt = 0; nt < 4; ++nt)
#pragma unroll
    for (int r = 0; r < 4; ++r) {
      int ti = mt * 16 + quad * 4 + r;
      int q  = nt * 16 + col;
      float val = tanhf(acc[nt][r] * (1.0f / 800.0f)) * alpha + att0t[(s * 64 + ti) * 64 + q];
      atttT[((size_t)((n * 3 + s) * 64) + q) * 64 + ti] = f2bf(val);
    }
}

// =============================================================================
// fused temporal merge per (n,v):
//   stage0: LDS y-tile yT[c128][t64] (stride 72) from y_cl
//   stage1: z[q][s*128+c] = sum_t yT[c][t] * att_tT[s][q][t]   (LDS, stride 392)
//   stage2: z1[q][o] = lrelu( z.Woutt'^T + ycl.Wdt1'^T + shiftC )
// =============================================================================
__global__ __launch_bounds__(256) void k_fused(
    const unsigned short* __restrict__ ycl,
    const unsigned short* __restrict__ atttT,
    const unsigned short* __restrict__ Woutt, const unsigned short* __restrict__ Wdt1,
    const float* __restrict__ shiftC, unsigned short* __restrict__ z1)
{
  __shared__ unsigned short z[64 * 392];   // 50176 B
  __shared__ unsigned short yT[128 * 72];  // 18432 B
  int b = blockIdx.x; int n = b / 25, v = b % 25;
  int wave = threadIdx.x >> 6; int lane = threadIdx.x & 63;
  int col = lane & 15, quad = lane >> 4;
  int tid = threadIdx.x;

  // stage 0: y tile transpose into LDS
  for (int i = tid; i < 128 * 64; i += 256) {
    int t = i >> 7, c = i & 127;
    yT[c * 72 + t] = ycl[(((size_t)(n * 64 + t)) * 25 + v) * 128 + c];
  }
  __syncthreads();

  // stage 1
  bf16x8 ya[2][2];  // [ci][reg]
#pragma unroll
  for (int ci = 0; ci < 2; ++ci) {
    int ctg = wave * 2 + ci;
    ya[ci][0] = *(const bf16x8*)&yT[(ctg * 16 + col) * 72 + quad * 8];
    ya[ci][1] = *(const bf16x8*)&yT[(ctg * 16 + col) * 72 + 32 + quad * 8];
  }
#pragma unroll
  for (int s = 0; s < 3; ++s) {
#pragma unroll
    for (int ci = 0; ci < 2; ++ci) {
      int ctg = wave * 2 + ci;
#pragma unroll
      for (int qt = 0; qt < 4; ++qt) {
        const unsigned short* bp = atttT + ((size_t)((n * 3 + s) * 64) + qt * 16 + col) * 64 + quad * 8;
        f32x4 acc = {0.f, 0.f, 0.f, 0.f};
        acc = MFMA(ya[ci][0], *(const bf16x8*)bp, acc);
        acc = MFMA(ya[ci][1], *(const bf16x8*)(bp + 32), acc);
        bf16x4 pk;
        pk[0] = f2bf(acc[0]); pk[1] = f2bf(acc[1]); pk[2] = f2bf(acc[2]); pk[3] = f2bf(acc[3]);
        *(bf16x4*)&z[(qt * 16 + col) * 392 + s * 128 + ctg * 16 + quad * 4] = pk;
      }
    }
  }
  __syncthreads();

  // stage 2
  f32x4 acc[2][4];
#pragma unroll
  for (int a = 0; a < 2; ++a)
#pragma unroll
    for (int q = 0; q < 4; ++q) acc[a][q] = (f32x4){0.f, 0.f, 0.f, 0.f};

  for (int ks = 0; ks < 12; ++ks) {
    bf16x8 afr[4];
#pragma unroll
    for (int qt = 0; qt < 4; ++qt)
      afr[qt] = *(const bf16x8*)&z[(qt * 16 + col) * 392 + ks * 32 + quad * 8];
#pragma unroll
    for (int oi = 0; oi < 2; ++oi) {
      int otg = wave * 2 + oi;
      bf16x8 bb = *(const bf16x8*)(Woutt + (size_t)(otg * 16 + col) * 384 + ks * 32 + quad * 8);
#pragma unroll
      for (int qt = 0; qt < 4; ++qt) acc[oi][qt] = MFMA(afr[qt], bb, acc[oi][qt]);
    }
  }
  for (int ks = 0; ks < 4; ++ks) {
    bf16x8 afr[4];
#pragma unroll
    for (int qt = 0; qt < 4; ++qt)
      afr[qt] = *(const bf16x8*)(ycl + (((size_t)(n * 64 + qt * 16 + col)) * 25 + v) * 128 + ks * 32 + quad * 8);
#pragma unroll
    for (int oi = 0; oi < 2; ++oi) {
      int otg = wave * 2 + oi;
      bf16x8 bb = *(const bf16x8*)(Wdt1 + (size_t)(otg * 16 + col) * 128 + ks * 32 + quad * 8);
#pragma unroll
      for (int qt = 0; qt < 4; ++qt) acc[oi][qt] = MFMA(afr[qt], bb, acc[oi][qt]);
    }
  }
#pragma unroll
  for (int oi = 0; oi < 2; ++oi) {
    int o = (wave * 2 + oi) * 16 + col;
    float sh = shiftC[o];
#pragma unroll
    for (int qt = 0; qt < 4; ++qt)
#pragma unroll
      for (int r = 0; r < 4; ++r) {
        int q = qt * 16 + quad * 4 + r;
        float val = acc[oi][qt][r] + sh;
        val = (val >= 0.f) ? val : 0.1f * val;
        z1[(((size_t)(n * 64 + q)) * 25 + v) * 128 + o] = f2bf(val);
      }
  }
}

// =============================================================================
extern "C" void kernel_launch(void* const* d_in, const int* in_sizes, int n_in,
                              void* d_out, int out_size, void* d_ws, size_t ws_size,
                              hipStream_t stream)
{
  const float* x       = (const float*)d_in[0];
  const float* w_qk_s  = (const float*)d_in[1];
  const float* b_qk_s  = (const float*)d_in[2];
  const float* alphas  = (const float*)d_in[3];
  const float* att0s   = (const float*)d_in[4];
  const float* w_outs  = (const float*)d_in[5];
  const float* b_outs  = (const float*)d_in[6];
  const float* bn_outs = (const float*)d_in[7];
  const float* w_ffs   = (const float*)d_in[8];
  const float* b_ffs   = (const float*)d_in[9];
  const float* bn_ffs  = (const float*)d_in[10];
  const float* w_ds1   = (const float*)d_in[11];
  const float* b_ds1   = (const float*)d_in[12];
  const float* bn_ds1  = (const float*)d_in[13];
  const float* w_ds2   = (const float*)d_in[14];
  const float* b_ds2   = (const float*)d_in[15];
  const float* bn_ds2  = (const float*)d_in[16];
  const float* w_qk_t  = (const float*)d_in[17];
  const float* b_qk_t  = (const float*)d_in[18];
  const float* alphat  = (const float*)d_in[19];
  const float* att0t   = (const float*)d_in[20];
  const float* w_outt  = (const float*)d_in[21];
  const float* b_outt  = (const float*)d_in[22];
  const float* bn_outt = (const float*)d_in[23];
  const float* w_fft   = (const float*)d_in[24];
  const float* b_fft   = (const float*)d_in[25];
  const float* bn_fft  = (const float*)d_in[26];
  const float* w_dt1   = (const float*)d_in[27];
  const float* b_dt1   = (const float*)d_in[28];
  const float* bn_dt1  = (const float*)d_in[29];
  const float* w_dt2   = (const float*)d_in[30];
  const float* b_dt2   = (const float*)d_in[31];
  const float* bn_dt2  = (const float*)d_in[32];

  char* ws = (char*)d_ws;
  unsigned short* WQS   = (unsigned short*)(ws + OFF_WQS);
  unsigned short* WQT   = (unsigned short*)(ws + OFF_WQT);
  unsigned short* WOUTS = (unsigned short*)(ws + OFF_WOUTS);
  unsigned short* WDS1  = (unsigned short*)(ws + OFF_WDS1);
  unsigned short* WFFS  = (unsigned short*)(ws + OFF_WFFS);
  unsigned short* WDS2  = (unsigned short*)(ws + OFF_WDS2);
  unsigned short* WOUTT = (unsigned short*)(ws + OFF_WOUTT);
  unsigned short* WDT1  = (unsigned short*)(ws + OFF_WDT1);
  unsigned short* WFFT  = (unsigned short*)(ws + OFF_WFFT);
  unsigned short* WDT2  = (unsigned short*)(ws + OFF_WDT2);
  float* SHS = (float*)(ws + OFF_SHS);
  float* SHT = (float*)(ws + OFF_SHT);
  float* SHA = (float*)(ws + OFF_SHA);
  float* SHB = (float*)(ws + OFF_SHB);
  float* SHC = (float*)(ws + OFF_SHC);
  float* SHD = (float*)(ws + OFF_SHD);
  unsigned short* ATTST = (unsigned short*)(ws + OFF_ATTST);
  unsigned short* ATTTT = (unsigned short*)(ws + OFF_ATTTT);
  unsigned short* XCL   = (unsigned short*)(ws + OFF_XCL);
  unsigned short* YCL   = (unsigned short*)(ws + OFF_YCL);
  unsigned short* RB    = (unsigned short*)(ws + OFF_RB);
  unsigned short* RA    = (unsigned short*)(ws + OFF_RA);

  k_prep<<<826, 256, 0, stream>>>(
      w_qk_s, b_qk_s, w_outs, b_outs, bn_outs, w_ffs, b_ffs, bn_ffs,
      w_ds1, b_ds1, bn_ds1, w_ds2, b_ds2, bn_ds2, w_qk_t, b_qk_t,
      w_outt, b_outt, bn_outt, w_fft, b_fft, bn_fft,
      w_dt1, b_dt1, bn_dt1, w_dt2, b_dt2, bn_dt2, ws);

  k_convert<<<N_ * T_, 256, 0, stream>>>(x, XCL);

  // qk_s conv: RA[pos][192] <- x_cl, PE folded in shiftS[o][v]
  k_conv<64, 0, 192, 1, 0, 0><<<P_ / 64, 256, 0, stream>>>(
      XCL, (const unsigned short*)nullptr, WQS, (const unsigned short*)nullptr, SHS, RA);

  k_att_s<<<N_ * S_, 64, 0, stream>>>(RA, alphas, att0s, ATTST);
  // ys -> RA (overwrites qk_s, which is dead)
  k_einsum_s<<<N_ * T_, 64, 0, stream>>>(x, ATTST, RA);

  // y1 = lrelu(outs(ys) + ds1(x)) -> RB
  k_conv<192, 64, 128, 0, 1, 0><<<P_ / 64, 256, 0, stream>>>(
      RA, XCL, WOUTS, WDS1, SHA, RB);

  // y = lrelu(ffs(y1) + ds2(x)) -> YCL
  k_conv<128, 64, 128, 0, 1, 0><<<P_ / 64, 256, 0, stream>>>(
      RB, XCL, WFFS, WDS2, SHB, YCL);

  // qk_t conv -> RA (ys dead), PE folded in shiftT[o][t]
  k_conv<128, 0, 192, 2, 0, 0><<<P_ / 64, 256, 0, stream>>>(
      YCL, (const unsigned short*)nullptr, WQT, (const unsigned short*)nullptr, SHT, RA);

  k_att_t<<<N_ * S_, 256, 0, stream>>>(RA, alphat, att0t, ATTTT);

  // z1 = lrelu(outt(einsum_t(y,att)) + dt1(y)) -> RB (y1 dead)
  k_fused<<<N_ * V_, 256, 0, stream>>>(YCL, ATTTT, WOUTT, WDT1, SHC, RB);

  // out = lrelu(fft(z1) + dt2(y)), fp32 NCTV
  k_conv<128, 128, 128, 0, 1, 2><<<P_ / 64, 256, 0, stream>>>(
      RB, YCL, WFFT, WDT2, SHD, d_out);
}

// Round 4
// 744.762 us; speedup vs baseline: 21.7607x; 1.5186x over previous
//
#include <hip/hip_runtime.h>
#include <math.h>

#define N_    128
#define CIN   64
#define COUT  128
#define CINT  32
#define S_    3
#define T_    64
#define V_    25
#define EPSF  1e-5f
#define LN1E4 9.210340371976184f
#define P_    (N_*T_*V_)   // 204800 positions

typedef __attribute__((ext_vector_type(8))) short bf16x8;
typedef __attribute__((ext_vector_type(4))) unsigned short bf16x4;
typedef __attribute__((ext_vector_type(4))) float f32x4;

#define MFMA(a,b,c) __builtin_amdgcn_mfma_f32_16x16x32_bf16(a,b,c,0,0,0)

// ---- workspace byte offsets --------------------------------------------------
#define OFF_WQS    0u          // 192x64 bf16           -> 24576
#define OFF_WQT    24576u      // 192x128               -> 73728
#define OFF_WOUTS  73728u      // 128x192 prescaled     -> 122880
#define OFF_WDS1   122880u     // 128x64                -> 139264
#define OFF_WFFS   139264u     // 128x128               -> 172032
#define OFF_WDS2   172032u     // 128x64                -> 188416
#define OFF_WOUTT  188416u     // 128x384               -> 286720
#define OFF_WDT1   286720u     // 128x128               -> 319488
#define OFF_WFFT   319488u     // 128x128               -> 352256
#define OFF_WDT2   352256u     // 128x128               -> 385024
#define OFF_WOV    385024u     // 192x64 bf16 (qk_s shift cols) -> 409600
#define OFF_WOT    409600u     // 192x64 bf16 (qk_t shift cols) -> 434176
#define OFF_SHA    434176u
#define OFF_SHB    434688u
#define OFF_SHC    435200u
#define OFF_SHD    435712u     //                       -> 436224
#define OFF_OV     436224u     // [1600][64] onehot(v) bf16 -> 641024
#define OFF_OT     641024u     // [1600][64] onehot(t) bf16 -> 845824
#define OFF_ATTST  845824u     // [n][s][32v][32u] bf16 -> 1632256
#define OFF_ATTTT  1632256u    // [n][s][64q][64t] bf16 -> 4777984
#define OFF_XCL    4777984u    // [pos][64]  bf16       -> 30992384
#define OFF_YCL    30992384u   // [pos][128] bf16 (y)   -> 83421184
#define OFF_RB     83421184u   // [pos][128] bf16 (y1 then z1) -> 135849984
#define OFF_RA     135849984u  // [pos][192] bf16 (qk_s -> ys -> qk_t) -> 214493184

__device__ __forceinline__ unsigned short f2bf(float f) {
  union { float f; unsigned int u; } v; v.f = f;
  unsigned int u = v.u;
  return (unsigned short)((u + 0x7FFFu + ((u >> 16) & 1u)) >> 16);
}
__device__ __forceinline__ float bnscale(const float* bn, int o) {
  return bn[o] * rsqrtf(bn[3*COUT + o] + EPSF);
}
__device__ __forceinline__ float bnshift(const float* bn, const float* b, int o) {
  return (b[o] - bn[2*COUT + o]) * bnscale(bn, o) + bn[COUT + o];
}
__device__ __forceinline__ float pe_val(int c, int p, float inv) {
  float freq = expf(-(float)(c >> 1) * inv);
  float arg = (float)p * freq;
  return (c & 1) ? cosf(arg) : sinf(arg);
}

// =============================================================================
// prep: bf16 weights (BN-prescaled), shift-folded weight cols, onehot tables
// =============================================================================
__global__ __launch_bounds__(256) void k_prep(
    const float* __restrict__ wqks, const float* __restrict__ bqks,
    const float* __restrict__ wouts, const float* __restrict__ bouts, const float* __restrict__ bnouts,
    const float* __restrict__ wffs, const float* __restrict__ bffs, const float* __restrict__ bnffs,
    const float* __restrict__ wds1, const float* __restrict__ bds1, const float* __restrict__ bnds1,
    const float* __restrict__ wds2, const float* __restrict__ bds2, const float* __restrict__ bnds2,
    const float* __restrict__ wqkt, const float* __restrict__ bqkt,
    const float* __restrict__ woutt, const float* __restrict__ boutt, const float* __restrict__ bnoutt,
    const float* __restrict__ wfft, const float* __restrict__ bfft, const float* __restrict__ bnfft,
    const float* __restrict__ wdt1, const float* __restrict__ bdt1, const float* __restrict__ bndt1,
    const float* __restrict__ wdt2, const float* __restrict__ bdt2, const float* __restrict__ bndt2,
    char* __restrict__ ws)
{
  int i = blockIdx.x * 256 + threadIdx.x;
  unsigned short* WQS   = (unsigned short*)(ws + OFF_WQS);
  unsigned short* WQT   = (unsigned short*)(ws + OFF_WQT);
  unsigned short* WOUTS = (unsigned short*)(ws + OFF_WOUTS);
  unsigned short* WDS1  = (unsigned short*)(ws + OFF_WDS1);
  unsigned short* WFFS  = (unsigned short*)(ws + OFF_WFFS);
  unsigned short* WDS2  = (unsigned short*)(ws + OFF_WDS2);
  unsigned short* WOUTT = (unsigned short*)(ws + OFF_WOUTT);
  unsigned short* WDT1  = (unsigned short*)(ws + OFF_WDT1);
  unsigned short* WFFT  = (unsigned short*)(ws + OFF_WFFT);
  unsigned short* WDT2  = (unsigned short*)(ws + OFF_WDT2);
  unsigned short* WOV   = (unsigned short*)(ws + OFF_WOV);
  unsigned short* WOT   = (unsigned short*)(ws + OFF_WOT);
  float* SHA = (float*)(ws + OFF_SHA);
  float* SHB = (float*)(ws + OFF_SHB);
  float* SHC = (float*)(ws + OFF_SHC);
  float* SHD = (float*)(ws + OFF_SHD);
  unsigned short* OV = (unsigned short*)(ws + OFF_OV);
  unsigned short* OT = (unsigned short*)(ws + OFF_OT);

  if (i < 12288) { WQS[i] = f2bf(wqks[i]); }
  else if (i < 36864) { int j = i - 12288; WQT[j] = f2bf(wqkt[j]); }
  else if (i < 61440) { int j = i - 36864; int o = j / 192; WOUTS[j] = f2bf(wouts[j] * bnscale(bnouts, o)); }
  else if (i < 69632) { int j = i - 61440; int o = j / 64;  WDS1[j]  = f2bf(wds1[j]  * bnscale(bnds1, o)); }
  else if (i < 86016) { int j = i - 69632; int o = j / 128; WFFS[j]  = f2bf(wffs[j]  * bnscale(bnffs, o)); }
  else if (i < 94208) { int j = i - 86016; int o = j / 64;  WDS2[j]  = f2bf(wds2[j]  * bnscale(bnds2, o)); }
  else if (i < 143360){ int j = i - 94208; int o = j / 384; WOUTT[j] = f2bf(woutt[j] * bnscale(bnoutt, o)); }
  else if (i < 159744){ int j = i - 143360; int o = j / 128; WDT1[j] = f2bf(wdt1[j] * bnscale(bndt1, o)); }
  else if (i < 176128){ int j = i - 159744; int o = j / 128; WFFT[j] = f2bf(wfft[j] * bnscale(bnfft, o)); }
  else if (i < 192512){ int j = i - 176128; int o = j / 128; WDT2[j] = f2bf(wdt2[j] * bnscale(bndt2, o)); }
  else if (i < 204800){ // WOV[o][u]: qk_s shift (bias + conv(pe_s)) as weight cols
    int j = i - 192512; int o = j >> 6, u = j & 63;
    float acc = 0.f;
    if (u < V_) {
      acc = bqks[o];
      const float inv = 2.0f * LN1E4 / (float)CIN;
      for (int c = 0; c < CIN; ++c) acc += wqks[o*CIN + c] * pe_val(c, u, inv);
    }
    WOV[j] = f2bf(acc);
  }
  else if (i < 217088){ // WOT[o][t]: qk_t shift
    int j = i - 204800; int o = j >> 6, t = j & 63;
    float acc = bqkt[o];
    const float inv = 2.0f * LN1E4 / (float)COUT;
    for (int c = 0; c < COUT; ++c) acc += wqkt[o*COUT + c] * pe_val(c, t, inv);
    WOT[j] = f2bf(acc);
  }
  else if (i < 217600){
    int j = i - 217088; int o = j & 127; int g = j >> 7;
    if (g == 0) SHA[o] = bnshift(bnouts, bouts, o) + bnshift(bnds1, bds1, o);
    if (g == 1) SHB[o] = bnshift(bnffs, bffs, o)   + bnshift(bnds2, bds2, o);
    if (g == 2) SHC[o] = bnshift(bnoutt, boutt, o) + bnshift(bndt1, bdt1, o);
    if (g == 3) SHD[o] = bnshift(bnfft, bfft, o)   + bnshift(bndt2, bdt2, o);
  }
  else if (i < 320000){ // OV[rem][u] = onehot(v)
    int j = i - 217600; int rem = j >> 6, u = j & 63;
    OV[j] = (u == rem % 25) ? (unsigned short)0x3F80 : (unsigned short)0;
  }
  else if (i < 422400){ // OT[rem][u] = onehot(t)
    int j = i - 320000; int rem = j >> 6, u = j & 63;
    OT[j] = (u == rem / 25) ? (unsigned short)0x3F80 : (unsigned short)0;
  }
}

// =============================================================================
// convert x fp32 NCTV -> x_cl [pos][64] bf16
// =============================================================================
__global__ __launch_bounds__(256) void k_convert(const float* __restrict__ x,
                                                 unsigned short* __restrict__ xcl)
{
  __shared__ float xs[64][26];
  int b = blockIdx.x; int n = b >> 6, t = b & 63; int tid = threadIdx.x;
  for (int i = tid; i < 1600; i += 256) {
    int c = i / 25, v = i % 25;
    xs[c][v] = x[(((size_t)(n*64 + c))*64 + t)*25 + v];
  }
  __syncthreads();
  size_t clbase = ((size_t)(n*64 + t)) * 1600;
  for (int i = tid; i < 1600; i += 256) { int v = i >> 6, c = i & 63; xcl[clbase + i] = f2bf(xs[c][v]); }
}

// =============================================================================
// weights-in-LDS dual GEMM conv.  Block = 256 threads = 4 waves x 64 pos.
// out[pos][o] = f( A1[pos,:K1].W1[o]^T + A2[row2,:K2].W2[o]^T (+ shift[o]) )
// A2MOD: row2 = pos % 1600 (onehot tables) else pos.
// OMODE: 0 bf16 channel-last [pos][NOFULL] ; 2 fp32 NCTV (requires NOSUB==NOFULL==128)
// grid = (P_/256, NOFULL/NOSUB)
// =============================================================================
template<int K1, int K2, int NOSUB, int NOFULL, int HASSHIFT, int LRELU, int OMODE, int A2MOD>
__global__ __launch_bounds__(256, 2) void k_conv(
    const unsigned short* __restrict__ A1, const unsigned short* __restrict__ A2,
    const unsigned short* __restrict__ W1, const unsigned short* __restrict__ W2,
    const float* __restrict__ shift, void* __restrict__ outp)
{
  constexpr int K   = K1 + K2;      // multiple of 64
  constexpr int NK  = K / 32;
  constexpr int NK1 = K1 / 32;
  constexpr int GR  = K / 8;        // 16B granules per row (multiple of 8)
  __shared__ __align__(16) unsigned short Wl[NOSUB * K];

  const int oy = blockIdx.y;
  // ---- stage weights to LDS (XOR-swizzled granules) ----
  for (int i = threadIdx.x; i < NOSUB * GR; i += 256) {
    int o = i / GR, c = i % GR;
    int og = oy * NOSUB + o;
    int k = c * 8;
    const unsigned short* src = (k < K1) ? (W1 + (size_t)og * K1 + k)
                                         : (W2 + (size_t)og * K2 + (k - K1));
    int cs = c ^ (o & 7);
    *(int4*)&Wl[o * K + cs * 8] = *(const int4*)src;
  }

  const int lane = threadIdx.x & 63;
  const int wave = threadIdx.x >> 6;
  const int col  = lane & 15;
  const int quad = lane >> 4;
  const int pos0 = blockIdx.x * 256 + wave * 64;

  // ---- preload A fragments (4 m-tiles x NK) ----
  bf16x8 a[4][NK];
  const int remw = pos0 % 1600;
#pragma unroll
  for (int m = 0; m < 4; ++m) {
    const int pos = pos0 + m * 16 + col;
#pragma unroll
    for (int ks = 0; ks < NK; ++ks) {
      const unsigned short* p;
      if (ks < NK1) {
        p = A1 + (size_t)pos * K1 + ks * 32;
      } else {
        int row = pos;
        if (A2MOD) { int r2 = remw + m * 16 + col; if (r2 >= 1600) r2 -= 1600; row = r2; }
        p = A2 + (size_t)row * K2 + (ks - NK1) * 32;
      }
      a[m][ks] = *(const bf16x8*)(p + quad * 8);
    }
  }

  // ---- store bases per m ----
  int sb[4];
#pragma unroll
  for (int m = 0; m < 4; ++m) {
    int pm = pos0 + m * 16 + quad * 4;
    if (OMODE == 0) sb[m] = pm * NOFULL + oy * NOSUB + col;
    else { int n = pm / 1600, rm = pm % 1600; sb[m] = n * 204800 + rm; }
  }

  __syncthreads();

  // ---- main loop over o-tiles ----
  for (int ot = 0; ot < NOSUB / 16; ++ot) {
    const int orow = ot * 16 + col;
    f32x4 acc[4];
#pragma unroll
    for (int m = 0; m < 4; ++m) acc[m] = (f32x4){0.f, 0.f, 0.f, 0.f};
#pragma unroll
    for (int ks = 0; ks < NK; ++ks) {
      int cs = (ks * 4 + quad) ^ (col & 7);
      bf16x8 w = *(const bf16x8*)&Wl[orow * K + cs * 8];
#pragma unroll
      for (int m = 0; m < 4; ++m) acc[m] = MFMA(a[m][ks], w, acc[m]);
    }
    float sh = 0.f;
    if (HASSHIFT) sh = shift[oy * NOSUB + orow];
    if (OMODE == 2) {
      float* of = (float*)outp;
#pragma unroll
      for (int m = 0; m < 4; ++m) {
        float4 o4;
        float v0 = acc[m][0] + sh, v1 = acc[m][1] + sh, v2 = acc[m][2] + sh, v3 = acc[m][3] + sh;
        if (LRELU) {
          v0 = v0 >= 0.f ? v0 : 0.1f * v0; v1 = v1 >= 0.f ? v1 : 0.1f * v1;
          v2 = v2 >= 0.f ? v2 : 0.1f * v2; v3 = v3 >= 0.f ? v3 : 0.1f * v3;
        }
        o4.x = v0; o4.y = v1; o4.z = v2; o4.w = v3;
        *(float4*)&of[(size_t)sb[m] + (size_t)orow * 1600] = o4;
      }
    } else {
      unsigned short* oc = (unsigned short*)outp;
#pragma unroll
      for (int m = 0; m < 4; ++m)
#pragma unroll
        for (int r = 0; r < 4; ++r) {
          float val = acc[m][r] + sh;
          if (LRELU) val = val >= 0.f ? val : 0.1f * val;
          oc[(size_t)(sb[m] + r * NOFULL) + ot * 16] = f2bf(val);
        }
    }
  }
}

// =============================================================================
// spatial attention logits: per (n,s), C[u25][v25], K=(t64 x c32)
// out: att_sT[n][s][v(32)][u(32)] bf16, tanh-scaled, u>=25 zeroed
// =============================================================================
__global__ __launch_bounds__(64) void k_att_s(const unsigned short* __restrict__ qks,
                                              const float* __restrict__ alphas,
                                              const float* __restrict__ att0s,
                                              unsigned short* __restrict__ attsT)
{
  int b = blockIdx.x; int n = b / 3, s = b % 3;
  int lane = threadIdx.x; int col = lane & 15, quad = lane >> 4;
  f32x4 acc[2][2];
#pragma unroll
  for (int a = 0; a < 2; ++a)
#pragma unroll
    for (int c = 0; c < 2; ++c) acc[a][c] = (f32x4){0.f, 0.f, 0.f, 0.f};

  for (int t = 0; t < 64; ++t) {
    size_t rowb = ((size_t)(n * 64 + t)) * 25;
    bf16x8 afr[2], bfr[2];
#pragma unroll
    for (int ut = 0; ut < 2; ++ut)
      afr[ut] = *(const bf16x8*)(qks + (rowb + ut * 16 + col) * 192 + s * 32 + quad * 8);
#pragma unroll
    for (int vt = 0; vt < 2; ++vt)
      bfr[vt] = *(const bf16x8*)(qks + (rowb + vt * 16 + col) * 192 + 96 + s * 32 + quad * 8);
#pragma unroll
    for (int ut = 0; ut < 2; ++ut)
#pragma unroll
      for (int vt = 0; vt < 2; ++vt)
        acc[ut][vt] = MFMA(afr[ut], bfr[vt], acc[ut][vt]);
  }
  float alpha = alphas[s];
#pragma unroll
  for (int ut = 0; ut < 2; ++ut)
#pragma unroll
    for (int vt = 0; vt < 2; ++vt)
#pragma unroll
      for (int r = 0; r < 4; ++r) {
        int u = ut * 16 + quad * 4 + r;
        int v = vt * 16 + col;
        if (v < V_) {
          float val = 0.f;
          if (u < V_)
            val = tanhf(acc[ut][vt][r] * (1.0f / 2048.0f)) * alpha + att0s[(s * 25 + u) * 25 + v];
          attsT[((size_t)((n * 3 + s) * 32) + v) * 32 + u] = f2bf(val);
        }
      }
}

// =============================================================================
// spatial einsum: per (n,t): ys[v][s*64+c] = sum_u att_sT[s][v][u] * x[c][t][u]
// =============================================================================
__global__ __launch_bounds__(64) void k_einsum_s(const float* __restrict__ x,
                                                 const unsigned short* __restrict__ attsT,
                                                 unsigned short* __restrict__ ys)
{
  int b = blockIdx.x; int n = b >> 6, t = b & 63;
  int lane = threadIdx.x; int col = lane & 15, quad = lane >> 4;
  bf16x8 bfr[4];
#pragma unroll
  for (int ct = 0; ct < 4; ++ct) {
    const float* p = x + ((size_t)(n * 64 + ct * 16 + col) * 64 + t) * 25;
    bf16x8 f;
#pragma unroll
    for (int j = 0; j < 8; ++j) {
      int u = quad * 8 + j;
      f[j] = (u < V_) ? (short)f2bf(p[u]) : (short)0;
    }
    bfr[ct] = f;
  }
  size_t posbase = ((size_t)(n * 64 + t)) * 25;
#pragma unroll
  for (int s = 0; s < 3; ++s) {
    bf16x8 afr[2];
#pragma unroll
    for (int vt = 0; vt < 2; ++vt)
      afr[vt] = *(const bf16x8*)(attsT + ((size_t)((n * 3 + s) * 32) + vt * 16 + col) * 32 + quad * 8);
#pragma unroll
    for (int vt = 0; vt < 2; ++vt)
#pragma unroll
      for (int ct = 0; ct < 4; ++ct) {
        f32x4 acc = {0.f, 0.f, 0.f, 0.f};
        acc = MFMA(afr[vt], bfr[ct], acc);
#pragma unroll
        for (int r = 0; r < 4; ++r) {
          int v = vt * 16 + quad * 4 + r;
          if (v < V_)
            ys[(posbase + v) * 192 + s * 64 + ct * 16 + col] = f2bf(acc[r]);
        }
      }
  }
}

// =============================================================================
// temporal attention logits: per (n,s): C[t64][q64], K=(v25 x c32)
// out att_tT[n][s][q][t] bf16
// =============================================================================
__global__ __launch_bounds__(256) void k_att_t(const unsigned short* __restrict__ qkt,
                                               const float* __restrict__ alphat,
                                               const float* __restrict__ att0t,
                                               unsigned short* __restrict__ atttT)
{
  int b = blockIdx.x; int n = b / 3, s = b % 3;
  int wave = threadIdx.x >> 6; int lane = threadIdx.x & 63;
  int col = lane & 15, quad = lane >> 4;
  int mt = wave;
  f32x4 acc[4];
#pragma unroll
  for (int q = 0; q < 4; ++q) acc[q] = (f32x4){0.f, 0.f, 0.f, 0.f};

  for (int v = 0; v < V_; ++v) {
    bf16x8 a = *(const bf16x8*)(qkt + (((size_t)(n * 64 + mt * 16 + col)) * 25 + v) * 192 + s * 32 + quad * 8);
#pragma unroll
    for (int nt = 0; nt < 4; ++nt) {
      bf16x8 bb = *(const bf16x8*)(qkt + (((size_t)(n * 64 + nt * 16 + col)) * 25 + v) * 192 + 96 + s * 32 + quad * 8);
      acc[nt] = MFMA(a, bb, acc[nt]);
    }
  }
  float alpha = alphat[s];
#pragma unroll
  for (int nt = 0; nt < 4; ++nt)
#pragma unroll
    for (int r = 0; r < 4; ++r) {
      int ti = mt * 16 + quad * 4 + r;
      int q  = nt * 16 + col;
      float val = tanhf(acc[nt][r] * (1.0f / 800.0f)) * alpha + att0t[(s * 64 + ti) * 64 + q];
      atttT[((size_t)((n * 3 + s) * 64) + q) * 64 + ti] = f2bf(val);
    }
}

// =============================================================================
// fused temporal merge per (n,v):
//   stage0: LDS y-tile yT[c128][t64] (stride 72) from y_cl
//   stage1: z[q][s*128+c] = sum_t yT[c][t] * att_tT[s][q][t]   (LDS, stride 392)
//   stage2: z1[q][o] = lrelu( z.Woutt'^T + ycl.Wdt1'^T + shiftC )
// =============================================================================
__global__ __launch_bounds__(256) void k_fused(
    const unsigned short* __restrict__ ycl,
    const unsigned short* __restrict__ atttT,
    const unsigned short* __restrict__ Woutt, const unsigned short* __restrict__ Wdt1,
    const float* __restrict__ shiftC, unsigned short* __restrict__ z1)
{
  __shared__ unsigned short z[64 * 392];   // 50176 B
  __shared__ unsigned short yT[128 * 72];  // 18432 B
  int b = blockIdx.x; int n = b / 25, v = b % 25;
  int wave = threadIdx.x >> 6; int lane = threadIdx.x & 63;
  int col = lane & 15, quad = lane >> 4;
  int tid = threadIdx.x;

  // stage 0: y tile transpose into LDS
  for (int i = tid; i < 128 * 64; i += 256) {
    int t = i >> 7, c = i & 127;
    yT[c * 72 + t] = ycl[(((size_t)(n * 64 + t)) * 25 + v) * 128 + c];
  }
  __syncthreads();

  // stage 1
  bf16x8 ya[2][2];  // [ci][reg]
#pragma unroll
  for (int ci = 0; ci < 2; ++ci) {
    int ctg = wave * 2 + ci;
    ya[ci][0] = *(const bf16x8*)&yT[(ctg * 16 + col) * 72 + quad * 8];
    ya[ci][1] = *(const bf16x8*)&yT[(ctg * 16 + col) * 72 + 32 + quad * 8];
  }
#pragma unroll
  for (int s = 0; s < 3; ++s) {
#pragma unroll
    for (int ci = 0; ci < 2; ++ci) {
      int ctg = wave * 2 + ci;
#pragma unroll
      for (int qt = 0; qt < 4; ++qt) {
        const unsigned short* bp = atttT + ((size_t)((n * 3 + s) * 64) + qt * 16 + col) * 64 + quad * 8;
        f32x4 acc = {0.f, 0.f, 0.f, 0.f};
        acc = MFMA(ya[ci][0], *(const bf16x8*)bp, acc);
        acc = MFMA(ya[ci][1], *(const bf16x8*)(bp + 32), acc);
        bf16x4 pk;
        pk[0] = f2bf(acc[0]); pk[1] = f2bf(acc[1]); pk[2] = f2bf(acc[2]); pk[3] = f2bf(acc[3]);
        *(bf16x4*)&z[(qt * 16 + col) * 392 + s * 128 + ctg * 16 + quad * 4] = pk;
      }
    }
  }
  __syncthreads();

  // stage 2
  f32x4 acc[2][4];
#pragma unroll
  for (int a = 0; a < 2; ++a)
#pragma unroll
    for (int q = 0; q < 4; ++q) acc[a][q] = (f32x4){0.f, 0.f, 0.f, 0.f};

  for (int ks = 0; ks < 12; ++ks) {
    bf16x8 afr[4];
#pragma unroll
    for (int qt = 0; qt < 4; ++qt)
      afr[qt] = *(const bf16x8*)&z[(qt * 16 + col) * 392 + ks * 32 + quad * 8];
#pragma unroll
    for (int oi = 0; oi < 2; ++oi) {
      int otg = wave * 2 + oi;
      bf16x8 bb = *(const bf16x8*)(Woutt + (size_t)(otg * 16 + col) * 384 + ks * 32 + quad * 8);
#pragma unroll
      for (int qt = 0; qt < 4; ++qt) acc[oi][qt] = MFMA(afr[qt], bb, acc[oi][qt]);
    }
  }
  for (int ks = 0; ks < 4; ++ks) {
    bf16x8 afr[4];
#pragma unroll
    for (int qt = 0; qt < 4; ++qt)
      afr[qt] = *(const bf16x8*)(ycl + (((size_t)(n * 64 + qt * 16 + col)) * 25 + v) * 128 + ks * 32 + quad * 8);
#pragma unroll
    for (int oi = 0; oi < 2; ++oi) {
      int otg = wave * 2 + oi;
      bf16x8 bb = *(const bf16x8*)(Wdt1 + (size_t)(otg * 16 + col) * 128 + ks * 32 + quad * 8);
#pragma unroll
      for (int qt = 0; qt < 4; ++qt) acc[oi][qt] = MFMA(afr[qt], bb, acc[oi][qt]);
    }
  }
#pragma unroll
  for (int oi = 0; oi < 2; ++oi) {
    int o = (wave * 2 + oi) * 16 + col;
    float sh = shiftC[o];
#pragma unroll
    for (int qt = 0; qt < 4; ++qt)
#pragma unroll
      for (int r = 0; r < 4; ++r) {
        int q = qt * 16 + quad * 4 + r;
        float val = acc[oi][qt][r] + sh;
        val = (val >= 0.f) ? val : 0.1f * val;
        z1[(((size_t)(n * 64 + q)) * 25 + v) * 128 + o] = f2bf(val);
      }
  }
}

// =============================================================================
extern "C" void kernel_launch(void* const* d_in, const int* in_sizes, int n_in,
                              void* d_out, int out_size, void* d_ws, size_t ws_size,
                              hipStream_t stream)
{
  const float* x       = (const float*)d_in[0];
  const float* w_qk_s  = (const float*)d_in[1];
  const float* b_qk_s  = (const float*)d_in[2];
  const float* alphas  = (const float*)d_in[3];
  const float* att0s   = (const float*)d_in[4];
  const float* w_outs  = (const float*)d_in[5];
  const float* b_outs  = (const float*)d_in[6];
  const float* bn_outs = (const float*)d_in[7];
  const float* w_ffs   = (const float*)d_in[8];
  const float* b_ffs   = (const float*)d_in[9];
  const float* bn_ffs  = (const float*)d_in[10];
  const float* w_ds1   = (const float*)d_in[11];
  const float* b_ds1   = (const float*)d_in[12];
  const float* bn_ds1  = (const float*)d_in[13];
  const float* w_ds2   = (const float*)d_in[14];
  const float* b_ds2   = (const float*)d_in[15];
  const float* bn_ds2  = (const float*)d_in[16];
  const float* w_qk_t  = (const float*)d_in[17];
  const float* b_qk_t  = (const float*)d_in[18];
  const float* alphat  = (const float*)d_in[19];
  const float* att0t   = (const float*)d_in[20];
  const float* w_outt  = (const float*)d_in[21];
  const float* b_outt  = (const float*)d_in[22];
  const float* bn_outt = (const float*)d_in[23];
  const float* w_fft   = (const float*)d_in[24];
  const float* b_fft   = (const float*)d_in[25];
  const float* bn_fft  = (const float*)d_in[26];
  const float* w_dt1   = (const float*)d_in[27];
  const float* b_dt1   = (const float*)d_in[28];
  const float* bn_dt1  = (const float*)d_in[29];
  const float* w_dt2   = (const float*)d_in[30];
  const float* b_dt2   = (const float*)d_in[31];
  const float* bn_dt2  = (const float*)d_in[32];

  char* ws = (char*)d_ws;
  unsigned short* WQS   = (unsigned short*)(ws + OFF_WQS);
  unsigned short* WQT   = (unsigned short*)(ws + OFF_WQT);
  unsigned short* WOUTS = (unsigned short*)(ws + OFF_WOUTS);
  unsigned short* WDS1  = (unsigned short*)(ws + OFF_WDS1);
  unsigned short* WFFS  = (unsigned short*)(ws + OFF_WFFS);
  unsigned short* WDS2  = (unsigned short*)(ws + OFF_WDS2);
  unsigned short* WOUTT = (unsigned short*)(ws + OFF_WOUTT);
  unsigned short* WDT1  = (unsigned short*)(ws + OFF_WDT1);
  unsigned short* WFFT  = (unsigned short*)(ws + OFF_WFFT);
  unsigned short* WDT2  = (unsigned short*)(ws + OFF_WDT2);
  unsigned short* WOV   = (unsigned short*)(ws + OFF_WOV);
  unsigned short* WOT   = (unsigned short*)(ws + OFF_WOT);
  float* SHA = (float*)(ws + OFF_SHA);
  float* SHB = (float*)(ws + OFF_SHB);
  float* SHC = (float*)(ws + OFF_SHC);
  float* SHD = (float*)(ws + OFF_SHD);
  unsigned short* OV    = (unsigned short*)(ws + OFF_OV);
  unsigned short* OT    = (unsigned short*)(ws + OFF_OT);
  unsigned short* ATTST = (unsigned short*)(ws + OFF_ATTST);
  unsigned short* ATTTT = (unsigned short*)(ws + OFF_ATTTT);
  unsigned short* XCL   = (unsigned short*)(ws + OFF_XCL);
  unsigned short* YCL   = (unsigned short*)(ws + OFF_YCL);
  unsigned short* RB    = (unsigned short*)(ws + OFF_RB);
  unsigned short* RA    = (unsigned short*)(ws + OFF_RA);

  k_prep<<<1650, 256, 0, stream>>>(
      w_qk_s, b_qk_s, w_outs, b_outs, bn_outs, w_ffs, b_ffs, bn_ffs,
      w_ds1, b_ds1, bn_ds1, w_ds2, b_ds2, bn_ds2, w_qk_t, b_qk_t,
      w_outt, b_outt, bn_outt, w_fft, b_fft, bn_fft,
      w_dt1, b_dt1, bn_dt1, w_dt2, b_dt2, bn_dt2, ws);

  k_convert<<<N_ * T_, 256, 0, stream>>>(x, XCL);

  // qk_s: RA[pos][192] = XCL.WQS^T + onehot(v).WOV^T   (pure GEMM, shift folded)
  k_conv<64, 64, 192, 192, 0, 0, 0, 1><<<dim3(P_ / 256, 1), 256, 0, stream>>>(
      XCL, OV, WQS, WOV, nullptr, RA);

  k_att_s<<<N_ * S_, 64, 0, stream>>>(RA, alphas, att0s, ATTST);
  // ys -> RA (qk_s dead)
  k_einsum_s<<<N_ * T_, 64, 0, stream>>>(x, ATTST, RA);

  // y1 = lrelu(outs(ys) + ds1(x)) -> RB
  k_conv<192, 64, 128, 128, 1, 1, 0, 0><<<dim3(P_ / 256, 1), 256, 0, stream>>>(
      RA, XCL, WOUTS, WDS1, SHA, RB);

  // y = lrelu(ffs(y1) + ds2(x)) -> YCL
  k_conv<128, 64, 128, 128, 1, 1, 0, 0><<<dim3(P_ / 256, 1), 256, 0, stream>>>(
      RB, XCL, WFFS, WDS2, SHB, YCL);

  // qk_t: RA[pos][192] = YCL.WQT^T + onehot(t).WOT^T  (two o-halves)
  k_conv<128, 64, 96, 192, 0, 0, 0, 1><<<dim3(P_ / 256, 2), 256, 0, stream>>>(
      YCL, OT, WQT, WOT, nullptr, RA);

  k_att_t<<<N_ * S_, 256, 0, stream>>>(RA, alphat, att0t, ATTTT);

  // z1 = lrelu(outt(einsum_t(y,att)) + dt1(y)) -> RB (y1 dead)
  k_fused<<<N_ * V_, 256, 0, stream>>>(YCL, ATTTT, WOUTT, WDT1, SHC, RB);

  // out = lrelu(fft(z1) + dt2(y)), fp32 NCTV
  k_conv<128, 128, 128, 128, 1, 1, 2, 0><<<dim3(P_ / 256, 1), 256, 0, stream>>>(
      RB, YCL, WFFT, WDT2, SHD, d_out);
}